// Round 4
// baseline (563.545 us; speedup 1.0000x reference)
//
#include <hip/hip_runtime.h>
#include <hip/hip_bf16.h>
#include <math.h>

#define B_DIM 4
#define SEQ   2048
#define EMB   1024
#define HEADS 8
#define DHEAD 128
#define M_TOK (B_DIM * SEQ)   /* 8192 */
#define FFDIM (4 * EMB)       /* 4096 */

typedef unsigned short u16;
typedef __attribute__((ext_vector_type(8))) short short8v;
typedef __attribute__((ext_vector_type(4))) float float4v;
typedef __attribute__((ext_vector_type(16))) float float16v;

__device__ __forceinline__ u16 f2b(float f) {
  union { float f; unsigned u; } a; a.f = f;
  unsigned u = a.u;
  u += 0x7fffu + ((u >> 16) & 1u);   // round-to-nearest-even
  return (u16)(u >> 16);
}

// native cast: compiler pairs these into v_cvt_pk_bf16_f32
__device__ __forceinline__ u16 f2b_hw(float f) {
  __hip_bfloat16 h = __float2bfloat16(f);
  return *(u16*)&h;
}

__device__ __forceinline__ float b2f(u16 u) {
  union { unsigned u; float f; } x; x.u = ((unsigned)u) << 16; return x.f;
}

__device__ __forceinline__ void gload16(const void* g, void* l) {
  __builtin_amdgcn_global_load_lds(
      (const __attribute__((address_space(1))) unsigned int*)g,
      (__attribute__((address_space(3))) unsigned int*)l, 16, 0, 0);
}

// all-inline gelu (tanh form; max |err| vs exact-erf gelu ~1e-3, NaN-safe)
__device__ __forceinline__ float gelu_inl(float v) {
  const float y = 0.7978845608028654f * (v + 0.044715f * v * v * v);
  const float e = __expf(2.0f * y);
  const float th = 1.0f - 2.0f / (e + 1.0f);
  return 0.5f * v * (1.0f + th);
}

// ---------------- merged prep: x->bf16 + 4 weight transpose-converts ----------
__device__ __forceinline__ void tcvt_body(const float* __restrict__ W,
    u16* __restrict__ Wt, int K, int N, int bx, int by, int tx, int ty,
    float (*t)[33]) {
  const int n0 = bx * 32, k0 = by * 32;
  for (int j = ty; j < 32; j += 8)
    t[j][tx] = W[(size_t)(k0 + j) * N + n0 + tx];
  __syncthreads();
  for (int j = ty; j < 32; j += 8)
    Wt[(size_t)(n0 + j) * K + k0 + tx] = f2b(t[tx][j]);
}

__global__ __launch_bounds__(256) void k_prep(
    const float* __restrict__ x, const float* __restrict__ wqkv_w,
    const float* __restrict__ proj_w, const float* __restrict__ lin1_w,
    const float* __restrict__ lin2_w, u16* __restrict__ xb,
    u16* __restrict__ wqkv_t, u16* __restrict__ proj_t,
    u16* __restrict__ lin1_t, u16* __restrict__ lin2_t) {
  __shared__ float t[32][33];
  const int bid = blockIdx.x, tid = threadIdx.x;
  if (bid < 8192) {  // x convert: 8192 blocks x 256 thr x float4
    const int i = bid * 256 + tid;
    const float4 v = ((const float4*)x)[i];
    unsigned long long pk = (unsigned long long)f2b(v.x)
        | ((unsigned long long)f2b(v.y) << 16)
        | ((unsigned long long)f2b(v.z) << 32)
        | ((unsigned long long)f2b(v.w) << 48);
    ((unsigned long long*)xb)[i] = pk;
    return;
  }
  const int tx = tid & 31, ty = tid >> 5;
  if (bid < 11264)
    tcvt_body(wqkv_w, wqkv_t, 1024, 3072, (bid - 8192) % 96, (bid - 8192) / 96, tx, ty, t);
  else if (bid < 12288)
    tcvt_body(proj_w, proj_t, 1024, 1024, (bid - 11264) % 32, (bid - 11264) / 32, tx, ty, t);
  else if (bid < 16384)
    tcvt_body(lin1_w, lin1_t, 1024, 4096, (bid - 12288) % 128, (bid - 12288) / 128, tx, ty, t);
  else
    tcvt_body(lin2_w, lin2_t, 4096, 1024, (bid - 16384) % 32, (bid - 16384) / 32, tx, ty, t);
}

// ---------------- GEMM: C[M,N] = A[M,K](bf16) @ Bt[N,K]^T(bf16) + epilogue ----
// (round-2 proven version: 128^2 tile, dbuf gload_lds, XCD swizzle)
template <int EPI>
__global__ __launch_bounds__(256, 2) void k_gemm(
    const u16* __restrict__ A, const u16* __restrict__ Bt,
    const float* __restrict__ bias, const float* __restrict__ res,
    void* __restrict__ out0, int M, int N, int K) {
  __shared__ __align__(16) u16 lds[2][2][128][32];
  const int tid = threadIdx.x;
  const int l = tid & 63, w = tid >> 6;
  const int g = l >> 4, lm = l & 15;
  const int wm = w >> 1, wn = w & 1;

  const int NBX = N >> 7;
  const int nwg = NBX * (M >> 7);
  const int wg = blockIdx.x;
  const int swz = (wg & 7) * (nwg >> 3) + (wg >> 3);   // nwg % 8 == 0 always here
  const int tn = swz % NBX, tm = swz / NBX;

  const size_t arow0 = (size_t)tm * 128;
  const size_t brow0 = (size_t)tn * 128;
  const int srow = l >> 2;          // 0..15 within a 16-row chunk
  const int scol = (l & 3) * 8;     // element offset within row

  float4v acc[4][4];
  const float4v vzero = {0.f, 0.f, 0.f, 0.f};
#pragma unroll
  for (int i = 0; i < 4; ++i)
#pragma unroll
    for (int j = 0; j < 4; ++j) acc[i][j] = vzero;

  const int nt = K / 32;
  auto stage = [&](int t, int buf) {
    const int k0 = t * 32;
#pragma unroll
    for (int i = 0; i < 2; ++i) {
      const int r = w * 32 + i * 16 + srow;
      gload16(A + (arow0 + r) * (size_t)K + k0 + scol, &lds[buf][0][w * 32 + i * 16][0]);
      gload16(Bt + (brow0 + r) * (size_t)K + k0 + scol, &lds[buf][1][w * 32 + i * 16][0]);
    }
  };

  stage(0, 0);
  __syncthreads();
  for (int t = 0; t < nt; ++t) {
    const int buf = t & 1;
    if (t + 1 < nt) stage(t + 1, buf ^ 1);
    short8v af[4], bf[4];
#pragma unroll
    for (int mf = 0; mf < 4; ++mf)
      af[mf] = *(const short8v*)&lds[buf][0][wm * 64 + mf * 16 + lm][g * 8];
#pragma unroll
    for (int nf = 0; nf < 4; ++nf)
      bf[nf] = *(const short8v*)&lds[buf][1][wn * 64 + nf * 16 + lm][g * 8];
#pragma unroll
    for (int mf = 0; mf < 4; ++mf)
#pragma unroll
      for (int nf = 0; nf < 4; ++nf)
        acc[mf][nf] = __builtin_amdgcn_mfma_f32_16x16x32_bf16(af[mf], bf[nf], acc[mf][nf], 0, 0, 0);
    __syncthreads();
  }

#pragma unroll
  for (int mf = 0; mf < 4; ++mf)
#pragma unroll
    for (int nf = 0; nf < 4; ++nf)
#pragma unroll
      for (int r = 0; r < 4; ++r) {
        const int row = tm * 128 + wm * 64 + mf * 16 + 4 * g + r;
        const int col = tn * 128 + wn * 64 + nf * 16 + lm;
        float v = acc[mf][nf][r] + bias[col];
        if constexpr (EPI == 0) {
          const int hh = col / 384;
          const int rem = col - hh * 384;
          const int d = rem / 3;
          const int wv = rem - d * 3;
          const int btok = row >> 11, ntok = row & 2047;
          u16* dst = (u16*)out0 + (size_t)wv * ((size_t)M_TOK * EMB)
                   + (((size_t)(btok * HEADS + hh) * SEQ + ntok) * DHEAD + d);
          *dst = f2b(v);
        } else if constexpr (EPI == 2) {
          ((u16*)out0)[(size_t)row * N + col] = f2b(gelu_inl(v));
        } else {
          const size_t idx = (size_t)row * N + col;
          ((float*)out0)[idx] = v + res[idx];
        }
      }
}

// ---------------- flash attention, split-KV: QBLK=128, KVBLK=32, 2 halves ----
// Each block: 4 waves x 32 q-rows, HALF the key range (1024 keys, 32 tiles of
// 32). Grid 1024, LDS 32 KiB, launch_bounds(256,4) -> 4 blocks/CU resident =
// 16 waves/CU = 4 waves/SIMD (2x round-2) to hide the serial softmax chain.
// Writes UNNORMALIZED partial O (bf16) + per-row (m,l) f32; k_mrg combines.
// Same verified per-tile math as round 2 (S1 half removed). XCD-grouped
// decode: blocks i%8==x cover 4 (b,h) pairs -> K/V L2-resident.
__global__ __launch_bounds__(256, 4) void k_attn(
    const u16* __restrict__ q, const u16* __restrict__ k,
    const u16* __restrict__ v, u16* __restrict__ opart,
    float2* __restrict__ ml) {
  __shared__ __align__(16) u16 KT[2][32 * 128];  // [buf][key][d] swz, rows 256 B
  __shared__ __align__(16) u16 VT[2][32 * 128];  // [buf][d][key] swz, rows 64 B
  const int tid = threadIdx.x;
  const int l = tid & 63, w = tid >> 6;        // w 0..3
  const int q32 = l & 31, hi = l >> 5;
  // decode: xcd = i%8; per XCD: 4 (b,h) x (16 q-tiles x 2 kv-halves)
  const int i = blockIdx.x;
  const int xcd = i & 7, j = i >> 3;           // j 0..127
  const int bh = xcd * 4 + (j >> 5);           // 0..31
  const int rem = j & 31;
  const int qt = rem >> 1;                     // 0..15
  const int half = rem & 1;                    // 0..1
  const int hh = bh & 7, bb = bh >> 3;
  const size_t base = (size_t)(bb * HEADS + hh) * SEQ * DHEAD;
  const size_t khalf = base + (size_t)half * 1024 * DHEAD;
  const int qrow0 = qt * 128 + w * 32;

  // Q fragments (B-operand): lane holds Q[q32][c*16 + hi*8 .. +7]
  short8v qf[8];
#pragma unroll
  for (int c = 0; c < 8; ++c)
    qf[c] = *(const short8v*)(q + base + (size_t)(qrow0 + q32) * DHEAD + c * 16 + hi * 8);

  float m = -1e30f, Sden = 0.f;
  float16v O[4];
#pragma unroll
  for (int nf = 0; nf < 4; ++nf)
#pragma unroll
    for (int r = 0; r < 16; ++r) O[nf][r] = 0.f;

  const int krow = tid >> 4;            // 0..15 (row within 16-row sweep)
  const int kseg = (tid & 15) * 16;     // byte col within 256-B row
  const int vp = tid & 15, vdg = tid >> 4;   // key-pair 0..15, d-group 0..15

  short8v va, vb;                       // V prefetch regs (keys 2vp,2vp+1)
  auto loadV = [&](int t) {
    const u16* s0p = v + khalf + ((size_t)t * 32 + 2 * vp) * DHEAD + vdg * 8;
    va = *(const short8v*)s0p;
    vb = *(const short8v*)(s0p + DHEAD);
  };
  auto writeV = [&](int b) {
#pragma unroll
    for (int jj = 0; jj < 8; ++jj) {
      const int d = vdg * 8 + jj;
      const unsigned pk = ((unsigned)(u16)va[jj]) | (((unsigned)(u16)vb[jj]) << 16);
      const int byte = d * 64 + ((4 * vp) ^ ((d & 3) << 4));
      *(unsigned*)((char*)&VT[b][0] + byte) = pk;
    }
  };
  auto stageK = [&](int t, int b) {
    const size_t kvbase = khalf + (size_t)t * 32 * DHEAD;
#pragma unroll
    for (int s = 0; s < 2; ++s) {
      const int r = s * 16 + krow;
      const int csrc = kseg ^ ((r & 7) << 4);
      gload16(k + kvbase + (size_t)r * DHEAD + (csrc >> 1),
              (u16*)&KT[b][0] + s * 2048 + tid * 8);
    }
  };

  // prologue: fill buffer 0
  loadV(0);
  stageK(0, 0);
  writeV(0);
  __syncthreads();

  for (int t = 0; t < 32; ++t) {
    const int buf = t & 1;
    const char* KTb = (const char*)&KT[buf][0];
    const char* VTb = (const char*)&VT[buf][0];
    // issue next-tile loads first: V->regs (early-issue), K->LDS (async DMA)
    if (t + 1 < 32) { loadV(t + 1); stageK(t + 1, buf ^ 1); }

    // ---- QK^T swapped: S[key][q] = mfma(A=K, B=Q); lane q = q32 ----
    float16v S0;
#pragma unroll
    for (int r = 0; r < 16; ++r) S0[r] = 0.f;
    __builtin_amdgcn_s_setprio(1);
#pragma unroll
    for (int c = 0; c < 8; ++c) {
      const int cb = (c * 32 + hi * 16) ^ ((q32 & 7) << 4);
      const short8v kf0 = *(const short8v*)(KTb + q32 * 256 + cb);
      S0 = __builtin_amdgcn_mfma_f32_32x32x16_bf16(kf0, qf[c], S0, 0, 0, 0);
    }
    __builtin_amdgcn_s_setprio(0);

    // ---- in-register softmax for query q32 (keys split across hi) ----
    float pm = -1e30f;
#pragma unroll
    for (int r = 0; r < 16; ++r) pm = fmaxf(pm, S0[r]);
    pm = fmaxf(pm, __shfl_xor(pm, 32));
    if (!__all(pm <= m + 8.0f)) {      // defer-max
      const float nm = fmaxf(m, pm);
      const float rsc = __expf(m - nm);
      m = nm;
      Sden *= rsc;
#pragma unroll
      for (int r = 0; r < 16; ++r) {
        const float rr_ = __shfl(rsc, (r & 3) + 8 * (r >> 2) + 4 * hi, 64);
#pragma unroll
        for (int nf = 0; nf < 4; ++nf) O[nf][r] *= rr_;
      }
    }
    float ps = 0.f;
#pragma unroll
    for (int r = 0; r < 16; ++r) { S0[r] = __expf(S0[r] - m); ps += S0[r]; }
    ps += __shfl_xor(ps, 32);
    Sden += ps;

    // ---- pack P to bf16 pairs (native casts -> cvt_pk) ----
    unsigned u0[8];
#pragma unroll
    for (int jj = 0; jj < 8; ++jj)
      u0[jj] = (unsigned)f2b_hw(S0[2 * jj]) | ((unsigned)f2b_hw(S0[2 * jj + 1]) << 16);

    // ---- PV: build A-frags via one cross-half swap per pair, 8 MFMA ----
#pragma unroll
    for (int ks = 0; ks < 2; ++ks) {
      const unsigned b0v = u0[4 * ks], b1v = u0[4 * ks + 1];
      const unsigned b2v = u0[4 * ks + 2], b3v = u0[4 * ks + 3];
      const unsigned send0 = hi ? b0v : b2v;
      const unsigned send1 = hi ? b1v : b3v;
      const unsigned rx0 = (unsigned)__shfl_xor((int)send0, 32);
      const unsigned rx1 = (unsigned)__shfl_xor((int)send1, 32);
      union { unsigned uu[4]; short8v s8; } pu;
      pu.uu[0] = hi ? rx0 : b0v;
      pu.uu[1] = hi ? rx1 : b1v;
      pu.uu[2] = hi ? b2v : rx0;
      pu.uu[3] = hi ? b3v : rx1;
      __builtin_amdgcn_s_setprio(1);
#pragma unroll
      for (int nf = 0; nf < 4; ++nf) {
        const int dr = nf * 32 + q32;
        const int vbyte = dr * 64 + ((ks * 32 + hi * 16) ^ ((dr & 3) << 4));
        const short8v vf = *(const short8v*)(VTb + vbyte);
        O[nf] = __builtin_amdgcn_mfma_f32_32x32x16_bf16(pu.s8, vf, O[nf], 0, 0, 0);
      }
      __builtin_amdgcn_s_setprio(0);
    }

    // ---- late half of next-tile V staging: regs -> LDS (after compute) ----
    if (t + 1 < 32) writeV(buf ^ 1);
    __syncthreads();
  }

  // ---- epilogue: write UNNORMALIZED partial O (bf16) + (m, l) per q-row ----
  const size_t orow = (size_t)half * 65536 + (size_t)(bb * 8 + hh) * 2048;
#pragma unroll
  for (int r = 0; r < 16; ++r) {
    const int cr = (r & 3) + 8 * (r >> 2) + 4 * hi;
    const int tok = qrow0 + cr;
    u16* dst = opart + (orow + tok) * 128;
#pragma unroll
    for (int nf = 0; nf < 4; ++nf)
      dst[nf * 32 + q32] = f2b_hw(O[nf][r]);
  }
  if (hi == 0)
    ml[orow + qrow0 + q32] = make_float2(m, Sden);
}

// ---------------- merge of the two KV-half partials -> attn_o (bf16) --------
__global__ __launch_bounds__(256) void k_mrg(const u16* __restrict__ opart,
    const float2* __restrict__ ml, u16* __restrict__ o) {
  const int idx = blockIdx.x * 256 + threadIdx.x;  // 0..2097151
  const int row = idx >> 5;                        // 0..65535 = (bb*8+hh)*2048+tok
  const int d0 = (idx & 31) * 4;
  const float2 ml1 = ml[row];
  const float2 ml2 = ml[65536 + row];
  const float mm = fmaxf(ml1.x, ml2.x);
  const float w1 = __expf(ml1.x - mm), w2 = __expf(ml2.x - mm);
  const float inv = 1.0f / ((w1 * ml1.y + w2 * ml2.y) * 32.0f);
  const ushort4 a = *(const ushort4*)(opart + (size_t)row * 128 + d0);
  const ushort4 b = *(const ushort4*)(opart + ((size_t)65536 + row) * 128 + d0);
  ushort4 rr;
  rr.x = f2b_hw((w1 * b2f(a.x) + w2 * b2f(b.x)) * inv);
  rr.y = f2b_hw((w1 * b2f(a.y) + w2 * b2f(b.y)) * inv);
  rr.z = f2b_hw((w1 * b2f(a.z) + w2 * b2f(b.z)) * inv);
  rr.w = f2b_hw((w1 * b2f(a.w) + w2 * b2f(b.w)) * inv);
  const int bb = row >> 14, hh = (row >> 11) & 7, tok = row & 2047;
  *(ushort4*)(o + ((size_t)(bb * 2048 + tok)) * 1024 + hh * 128 + d0) = rr;
}

// ---------------- layernorm over 1024 ----------------
// MODE 0: write f32 + bf16; MODE 1: f32 only (may be in-place)
template <int MODE>
__global__ __launch_bounds__(256) void k_ln(const float* __restrict__ in,
    const float* __restrict__ gw, const float* __restrict__ bw,
    float* __restrict__ outf, u16* __restrict__ outb) {
  __shared__ float ps[4], pq[4];
  const int row = blockIdx.x;
  const int t = threadIdx.x;
  const float4 v = ((const float4*)(in + (size_t)row * EMB))[t];
  float s = v.x + v.y + v.z + v.w;
  float sq = v.x * v.x + v.y * v.y + v.z * v.z + v.w * v.w;
#pragma unroll
  for (int d = 1; d < 64; d <<= 1) { s += __shfl_xor(s, d); sq += __shfl_xor(sq, d); }
  const int l = t & 63, w = t >> 6;
  if (l == 0) { ps[w] = s; pq[w] = sq; }
  __syncthreads();
  s = ps[0] + ps[1] + ps[2] + ps[3];
  sq = pq[0] + pq[1] + pq[2] + pq[3];
  const float mean = s * (1.0f / 1024.0f);
  const float var = sq * (1.0f / 1024.0f) - mean * mean;
  const float rs = rsqrtf(var + 1e-5f);
  const float4 gv = ((const float4*)gw)[t];
  const float4 bv = ((const float4*)bw)[t];
  float4 ov;
  ov.x = (v.x - mean) * rs * gv.x + bv.x;
  ov.y = (v.y - mean) * rs * gv.y + bv.y;
  ov.z = (v.z - mean) * rs * gv.z + bv.z;
  ov.w = (v.w - mean) * rs * gv.w + bv.w;
  ((float4*)(outf + (size_t)row * EMB))[t] = ov;
  if constexpr (MODE == 0) {
    unsigned long long pk = (unsigned long long)f2b(ov.x)
        | ((unsigned long long)f2b(ov.y) << 16)
        | ((unsigned long long)f2b(ov.z) << 32)
        | ((unsigned long long)f2b(ov.w) << 48);
    ((unsigned long long*)(outb + (size_t)row * EMB))[t] = pk;
  }
}

extern "C" void kernel_launch(void* const* d_in, const int* in_sizes, int n_in,
                              void* d_out, int out_size, void* d_ws, size_t ws_size,
                              hipStream_t stream) {
  const float* x      = (const float*)d_in[0];
  const float* wqkv_w = (const float*)d_in[1];
  const float* wqkv_b = (const float*)d_in[2];
  const float* proj_w = (const float*)d_in[3];
  const float* proj_b = (const float*)d_in[4];
  const float* lin1_w = (const float*)d_in[5];
  const float* lin1_b = (const float*)d_in[6];
  const float* lin2_w = (const float*)d_in[7];
  const float* lin2_b = (const float*)d_in[8];
  const float* ln_g   = (const float*)d_in[9];
  const float* ln_b   = (const float*)d_in[10];

  char* ws = (char*)d_ws;
  // arena (bytes)
  u16*   wqkv_t = (u16*)(ws + 0);                       //  6,291,456
  u16*   proj_t = (u16*)(ws + 6291456);                 //  2,097,152
  u16*   lin1_t = (u16*)(ws + 8388608);                 //  8,388,608
  u16*   lin2_t = (u16*)(ws + 16777216);                //  8,388,608
  u16*   qbuf   = (u16*)(ws + 25165824);                // 16 MiB x3 (q,k,v)
  u16*   kbuf   = (u16*)(ws + 25165824 + 16777216);
  u16*   vbuf   = (u16*)(ws + 25165824 + 33554432);
  u16*   xb     = (u16*)(ws + 75497472);                // 16 MiB; later attn_out
  u16*   attn_o = (u16*)(ws + 75497472);
  float* res1   = (float*)(ws + 92274688);              // 32 MiB
  u16*   hbuf   = (u16*)(ws + 92274688);                // 64 MiB (over res1, later)
  u16*   opart  = (u16*)(ws + 92274688);                // 32 MiB partial O (pre-res1)
  float2* mlprt = (float2*)(ws + 0);                    // 1 MiB (over dead wqkv_t)
  float* x1f    = (float*)(ws + 25165824);              // 32 MiB (over q,k)
  u16*   x1b    = (u16*)(ws + 58720256);                // 16 MiB (over v)
  float* outf   = (float*)d_out;

  // merged prep: x->bf16 + all weight transpose-converts (one launch)
  k_prep<<<20480, 256, 0, stream>>>(x, wqkv_w, proj_w, lin1_w, lin2_w,
                                    xb, wqkv_t, proj_t, lin1_t, lin2_t);

  // QKV GEMM + head-interleave scatter (1-D swizzled grid)
  k_gemm<0><<<(3 * EMB / 128) * (M_TOK / 128), 256, 0, stream>>>(
      xb, wqkv_t, wqkv_b, nullptr, (void*)qbuf, M_TOK, 3 * EMB, EMB);
  // attention core: split-KV halves, 1024 blocks x 256 thr -> partials
  k_attn<<<1024, 256, 0, stream>>>(qbuf, kbuf, vbuf, opart, mlprt);
  // merge partials -> attn_o (bf16, token-major)
  k_mrg<<<8192, 256, 0, stream>>>(opart, mlprt, attn_o);
  // proj + residual(x) -> res1 (f32)
  k_gemm<1><<<(EMB / 128) * (M_TOK / 128), 256, 0, stream>>>(
      attn_o, proj_t, proj_b, x, (void*)res1, M_TOK, EMB, EMB);
  // LN1 -> x1f (f32) + x1b (bf16)
  k_ln<0><<<M_TOK, 256, 0, stream>>>(res1, ln_g, ln_b, x1f, x1b);
  // lin1 + gelu -> h (bf16)
  k_gemm<2><<<(FFDIM / 128) * (M_TOK / 128), 256, 0, stream>>>(
      x1b, lin1_t, lin1_b, nullptr, (void*)hbuf, M_TOK, FFDIM, EMB);
  // lin2 + residual(x1f) -> d_out (f32, pre-LN)
  k_gemm<3><<<(EMB / 128) * (M_TOK / 128), 256, 0, stream>>>(
      hbuf, lin2_t, lin2_b, x1f, (void*)outf, M_TOK, EMB, FFDIM);
  // LN2 in-place on d_out
  k_ln<1><<<M_TOK, 256, 0, stream>>>(outf, ln_g, ln_b, outf, nullptr);
}

// Round 5
// 459.436 us; speedup vs baseline: 1.2266x; 1.2266x over previous
//
#include <hip/hip_runtime.h>
#include <hip/hip_bf16.h>
#include <math.h>

#define B_DIM 4
#define SEQ   2048
#define EMB   1024
#define HEADS 8
#define DHEAD 128
#define M_TOK (B_DIM * SEQ)   /* 8192 */
#define FFDIM (4 * EMB)       /* 4096 */

typedef unsigned short u16;
typedef __attribute__((ext_vector_type(8))) short short8v;
typedef __attribute__((ext_vector_type(4))) float float4v;
typedef __attribute__((ext_vector_type(16))) float float16v;

__device__ __forceinline__ u16 f2b(float f) {
  union { float f; unsigned u; } a; a.f = f;
  unsigned u = a.u;
  u += 0x7fffu + ((u >> 16) & 1u);   // round-to-nearest-even
  return (u16)(u >> 16);
}

// native cast: compiler pairs these into v_cvt_pk_bf16_f32
__device__ __forceinline__ u16 f2b_hw(float f) {
  __hip_bfloat16 h = __float2bfloat16(f);
  return *(u16*)&h;
}

__device__ __forceinline__ void gload16(const void* g, void* l) {
  __builtin_amdgcn_global_load_lds(
      (const __attribute__((address_space(1))) unsigned int*)g,
      (__attribute__((address_space(3))) unsigned int*)l, 16, 0, 0);
}

// all-inline gelu (tanh form; max |err| vs exact-erf gelu ~1e-3, NaN-safe)
__device__ __forceinline__ float gelu_inl(float v) {
  const float y = 0.7978845608028654f * (v + 0.044715f * v * v * v);
  const float e = __expf(2.0f * y);
  const float th = 1.0f - 2.0f / (e + 1.0f);
  return 0.5f * v * (1.0f + th);
}

// ---------------- merged prep: x->bf16 + 4 weight transpose-converts ----------
__device__ __forceinline__ void tcvt_body(const float* __restrict__ W,
    u16* __restrict__ Wt, int K, int N, int bx, int by, int tx, int ty,
    float (*t)[33]) {
  const int n0 = bx * 32, k0 = by * 32;
  for (int j = ty; j < 32; j += 8)
    t[j][tx] = W[(size_t)(k0 + j) * N + n0 + tx];
  __syncthreads();
  for (int j = ty; j < 32; j += 8)
    Wt[(size_t)(n0 + j) * K + k0 + tx] = f2b(t[tx][j]);
}

__global__ __launch_bounds__(256) void k_prep(
    const float* __restrict__ x, const float* __restrict__ wqkv_w,
    const float* __restrict__ proj_w, const float* __restrict__ lin1_w,
    const float* __restrict__ lin2_w, u16* __restrict__ xb,
    u16* __restrict__ wqkv_t, u16* __restrict__ proj_t,
    u16* __restrict__ lin1_t, u16* __restrict__ lin2_t) {
  __shared__ float t[32][33];
  const int bid = blockIdx.x, tid = threadIdx.x;
  if (bid < 8192) {  // x convert: 8192 blocks x 256 thr x float4
    const int i = bid * 256 + tid;
    const float4 v = ((const float4*)x)[i];
    unsigned long long pk = (unsigned long long)f2b(v.x)
        | ((unsigned long long)f2b(v.y) << 16)
        | ((unsigned long long)f2b(v.z) << 32)
        | ((unsigned long long)f2b(v.w) << 48);
    ((unsigned long long*)xb)[i] = pk;
    return;
  }
  const int tx = tid & 31, ty = tid >> 5;
  if (bid < 11264)
    tcvt_body(wqkv_w, wqkv_t, 1024, 3072, (bid - 8192) % 96, (bid - 8192) / 96, tx, ty, t);
  else if (bid < 12288)
    tcvt_body(proj_w, proj_t, 1024, 1024, (bid - 11264) % 32, (bid - 11264) / 32, tx, ty, t);
  else if (bid < 16384)
    tcvt_body(lin1_w, lin1_t, 1024, 4096, (bid - 12288) % 128, (bid - 12288) / 128, tx, ty, t);
  else
    tcvt_body(lin2_w, lin2_t, 4096, 1024, (bid - 16384) % 32, (bid - 16384) / 32, tx, ty, t);
}

// ---------------- GEMM: C[M,N] = A[M,K](bf16) @ Bt[N,K]^T(bf16) + epilogue ----
// 1-D grid with bijective XCD swizzle (T1). (proven 128^2 m97-structure)
template <int EPI>
__global__ __launch_bounds__(256, 2) void k_gemm(
    const u16* __restrict__ A, const u16* __restrict__ Bt,
    const float* __restrict__ bias, const float* __restrict__ res,
    void* __restrict__ out0, int M, int N, int K) {
  __shared__ __align__(16) u16 lds[2][2][128][32];
  const int tid = threadIdx.x;
  const int l = tid & 63, w = tid >> 6;
  const int g = l >> 4, lm = l & 15;
  const int wm = w >> 1, wn = w & 1;

  const int NBX = N >> 7;
  const int nwg = NBX * (M >> 7);
  const int wg = blockIdx.x;
  const int swz = (wg & 7) * (nwg >> 3) + (wg >> 3);   // nwg % 8 == 0 always here
  const int tn = swz % NBX, tm = swz / NBX;

  const size_t arow0 = (size_t)tm * 128;
  const size_t brow0 = (size_t)tn * 128;
  const int srow = l >> 2;          // 0..15 within a 16-row chunk
  const int scol = (l & 3) * 8;     // element offset within row

  float4v acc[4][4];
  const float4v vzero = {0.f, 0.f, 0.f, 0.f};
#pragma unroll
  for (int i = 0; i < 4; ++i)
#pragma unroll
    for (int j = 0; j < 4; ++j) acc[i][j] = vzero;

  const int nt = K / 32;
  auto stage = [&](int t, int buf) {
    const int k0 = t * 32;
#pragma unroll
    for (int i = 0; i < 2; ++i) {
      const int r = w * 32 + i * 16 + srow;
      gload16(A + (arow0 + r) * (size_t)K + k0 + scol, &lds[buf][0][w * 32 + i * 16][0]);
      gload16(Bt + (brow0 + r) * (size_t)K + k0 + scol, &lds[buf][1][w * 32 + i * 16][0]);
    }
  };

  stage(0, 0);
  __syncthreads();
  for (int t = 0; t < nt; ++t) {
    const int buf = t & 1;
    if (t + 1 < nt) stage(t + 1, buf ^ 1);
    short8v af[4], bf[4];
#pragma unroll
    for (int mf = 0; mf < 4; ++mf)
      af[mf] = *(const short8v*)&lds[buf][0][wm * 64 + mf * 16 + lm][g * 8];
#pragma unroll
    for (int nf = 0; nf < 4; ++nf)
      bf[nf] = *(const short8v*)&lds[buf][1][wn * 64 + nf * 16 + lm][g * 8];
#pragma unroll
    for (int mf = 0; mf < 4; ++mf)
#pragma unroll
      for (int nf = 0; nf < 4; ++nf)
        acc[mf][nf] = __builtin_amdgcn_mfma_f32_16x16x32_bf16(af[mf], bf[nf], acc[mf][nf], 0, 0, 0);
    __syncthreads();
  }

#pragma unroll
  for (int mf = 0; mf < 4; ++mf)
#pragma unroll
    for (int nf = 0; nf < 4; ++nf)
#pragma unroll
      for (int r = 0; r < 4; ++r) {
        const int row = tm * 128 + wm * 64 + mf * 16 + 4 * g + r;
        const int col = tn * 128 + wn * 64 + nf * 16 + lm;
        float v = acc[mf][nf][r] + bias[col];
        if constexpr (EPI == 0) {
          const int hh = col / 384;
          const int rem = col - hh * 384;
          const int d = rem / 3;
          const int wv = rem - d * 3;
          const int btok = row >> 11, ntok = row & 2047;
          u16* dst = (u16*)out0 + (size_t)wv * ((size_t)M_TOK * EMB)
                   + (((size_t)(btok * HEADS + hh) * SEQ + ntok) * DHEAD + d);
          *dst = f2b(v);
        } else if constexpr (EPI == 2) {
          ((u16*)out0)[(size_t)row * N + col] = f2b(gelu_inl(v));
        } else {
          const size_t idx = (size_t)row * N + col;
          ((float*)out0)[idx] = v + res[idx];
        }
      }
}

// ---------------- flash attention: swapped-QK^T 32x32, QBLK=256, KVBLK=128 ----
// q,k,v: bf16 [b,h,2048,128]; o: bf16 [8192,1024] (token-major, h*128+d cols)
// 8 waves x 32 q-rows; 128-key tiles, single-buffered (round-0 structure,
// fastest measured). T15 att[2]: QK^T of BOTH 64-key sub-tiles issued before
// the first softmax -> softmax(0) VALU overlaps QK(1) MFMAs; softmax(1)
// overlaps PV(0). fmax/sum reductions use split accumulators (shorter
// serial chain). XOR-swizzled K/VT, in-register softmax/P, defer-max,
// cvt_pk pack, setprio on MFMA.
__global__ __launch_bounds__(512, 2) void k_attn(
    const u16* __restrict__ q, const u16* __restrict__ k,
    const u16* __restrict__ v, u16* __restrict__ o) {
  __shared__ __align__(16) u16 KT[128 * 128];  // [key][d] swizzled, rows 256 B
  __shared__ __align__(16) u16 VT[128 * 128];  // [d][key] swizzled, rows 256 B
  const int tid = threadIdx.x;
  const int l = tid & 63, w = tid >> 6;        // w 0..7
  const int q32 = l & 31, hi = l >> 5;
  const int qt = blockIdx.x, hh = blockIdx.y, bb = blockIdx.z;
  const size_t base = (size_t)(bb * HEADS + hh) * SEQ * DHEAD;
  const int qrow0 = qt * 256 + w * 32;

  // Q fragments (B-operand): lane holds Q[q32][c*16 + hi*8 .. +7]
  short8v qf[8];
#pragma unroll
  for (int c = 0; c < 8; ++c)
    qf[c] = *(const short8v*)(q + base + (size_t)(qrow0 + q32) * DHEAD + c * 16 + hi * 8);

  float m = -1e30f, Sden = 0.f;
  float16v O[4];
#pragma unroll
  for (int nf = 0; nf < 4; ++nf)
#pragma unroll
    for (int r = 0; r < 16; ++r) O[nf][r] = 0.f;

  const int krow = tid >> 4;            // 0..31 (row within 32-row sweep)
  const int kseg = (tid & 15) * 16;     // byte col within 256-B row
  const int vp = tid & 31, vdg = tid >> 5;   // vdg 0..15

  for (int kvt = 0; kvt < 16; ++kvt) {
    const size_t kvbase = base + (size_t)kvt * 128 * DHEAD;
    // ---- stage K (128 keys) via global_load_lds: linear dest, pre-swz src ----
#pragma unroll
    for (int s = 0; s < 4; ++s) {
      const int r = s * 32 + krow;
      const int csrc = kseg ^ ((r & 7) << 4);
      gload16(k + kvbase + r * DHEAD + (csrc >> 1), (u16*)KT + s * 4096 + tid * 8);
    }
    // ---- stage V transposed (128 keys) with swizzled writes: VT[d][key] ----
#pragma unroll
    for (int kk = 0; kk < 2; ++kk) {
      const int d0 = vdg * 8;
      const u16* s0p = v + kvbase + (size_t)(kk * 64 + 2 * vp) * DHEAD + d0;
      const short8v a = *(const short8v*)s0p;
      const short8v b2 = *(const short8v*)(s0p + DHEAD);
#pragma unroll
      for (int j = 0; j < 8; ++j) {
        const unsigned pk = ((unsigned)(u16)a[j]) | (((unsigned)(u16)b2[j]) << 16);
        const int byte = ((d0 + j) * 256 + kk * 128 + 4 * vp) ^ (((d0 + j) & 7) << 4);
        *(unsigned*)((char*)VT + byte) = pk;
      }
    }
    __syncthreads();

    // ---- T15: QK^T for BOTH sub-tiles before any softmax ----
    float16v Sa0, Sa1, Sb0, Sb1;
#pragma unroll
    for (int r = 0; r < 16; ++r) { Sa0[r] = 0.f; Sa1[r] = 0.f; Sb0[r] = 0.f; Sb1[r] = 0.f; }
    __builtin_amdgcn_s_setprio(1);
#pragma unroll
    for (int c = 0; c < 8; ++c) {           // sub 0: keys 0..63
      const int cb = (c * 32 + hi * 16) ^ ((q32 & 7) << 4);
      const short8v kf0 = *(const short8v*)((const char*)KT + q32 * 256 + cb);
      const short8v kf1 = *(const short8v*)((const char*)KT + (32 + q32) * 256 + cb);
      Sa0 = __builtin_amdgcn_mfma_f32_32x32x16_bf16(kf0, qf[c], Sa0, 0, 0, 0);
      Sa1 = __builtin_amdgcn_mfma_f32_32x32x16_bf16(kf1, qf[c], Sa1, 0, 0, 0);
    }
#pragma unroll
    for (int c = 0; c < 8; ++c) {           // sub 1: keys 64..127
      const int cb = (c * 32 + hi * 16) ^ ((q32 & 7) << 4);
      const short8v kf2 = *(const short8v*)((const char*)KT + (64 + q32) * 256 + cb);
      const short8v kf3 = *(const short8v*)((const char*)KT + (96 + q32) * 256 + cb);
      Sb0 = __builtin_amdgcn_mfma_f32_32x32x16_bf16(kf2, qf[c], Sb0, 0, 0, 0);
      Sb1 = __builtin_amdgcn_mfma_f32_32x32x16_bf16(kf3, qf[c], Sb1, 0, 0, 0);
    }
    __builtin_amdgcn_s_setprio(0);

#pragma unroll
    for (int sub = 0; sub < 2; ++sub) {
      float16v& S0 = sub ? Sb0 : Sa0;
      float16v& S1 = sub ? Sb1 : Sa1;

      // ---- in-register softmax for query q32 (keys split across hi) ----
      // split-accumulator max (shorter dependency chain; assoc. of fmax)
      float p0 = -1e30f, p1 = -1e30f, p2 = -1e30f, p3 = -1e30f;
#pragma unroll
      for (int r = 0; r < 16; r += 4) {
        p0 = fmaxf(p0, fmaxf(S0[r],     S1[r]));
        p1 = fmaxf(p1, fmaxf(S0[r + 1], S1[r + 1]));
        p2 = fmaxf(p2, fmaxf(S0[r + 2], S1[r + 2]));
        p3 = fmaxf(p3, fmaxf(S0[r + 3], S1[r + 3]));
      }
      float pm = fmaxf(fmaxf(p0, p1), fmaxf(p2, p3));
      pm = fmaxf(pm, __shfl_xor(pm, 32));
      if (!__all(pm <= m + 8.0f)) {      // defer-max
        const float nm = fmaxf(m, pm);
        const float rsc = __expf(m - nm);
        m = nm;
        Sden *= rsc;
#pragma unroll
        for (int r = 0; r < 16; ++r) {
          const float rr_ = __shfl(rsc, (r & 3) + 8 * (r >> 2) + 4 * hi, 64);
#pragma unroll
          for (int nf = 0; nf < 4; ++nf) O[nf][r] *= rr_;
        }
      }
      float psa = 0.f, psb = 0.f;
#pragma unroll
      for (int r = 0; r < 16; ++r) {
        S0[r] = __expf(S0[r] - m); psa += S0[r];
        S1[r] = __expf(S1[r] - m); psb += S1[r];
      }
      float ps = psa + psb;
      ps += __shfl_xor(ps, 32);
      Sden += ps;

      // ---- pack P to bf16 pairs (native casts -> cvt_pk) ----
      unsigned u0[8], u1[8];
#pragma unroll
      for (int j = 0; j < 8; ++j) {
        u0[j] = (unsigned)f2b_hw(S0[2 * j]) | ((unsigned)f2b_hw(S0[2 * j + 1]) << 16);
        u1[j] = (unsigned)f2b_hw(S1[2 * j]) | ((unsigned)f2b_hw(S1[2 * j + 1]) << 16);
      }

      // ---- PV: build A-frags via one cross-half swap per pair, 16 MFMA ----
#pragma unroll
      for (int ks = 0; ks < 4; ++ks) {
        const int k1 = ks & 1;
        unsigned b0v, b1v, b2v, b3v;
        if (ks < 2) { b0v = u0[4 * k1]; b1v = u0[4 * k1 + 1]; b2v = u0[4 * k1 + 2]; b3v = u0[4 * k1 + 3]; }
        else        { b0v = u1[4 * k1]; b1v = u1[4 * k1 + 1]; b2v = u1[4 * k1 + 2]; b3v = u1[4 * k1 + 3]; }
        const unsigned send0 = hi ? b0v : b2v;
        const unsigned send1 = hi ? b1v : b3v;
        const unsigned rx0 = (unsigned)__shfl_xor((int)send0, 32);
        const unsigned rx1 = (unsigned)__shfl_xor((int)send1, 32);
        union { unsigned uu[4]; short8v s8; } pu;
        pu.uu[0] = hi ? rx0 : b0v;
        pu.uu[1] = hi ? rx1 : b1v;
        pu.uu[2] = hi ? b2v : rx0;
        pu.uu[3] = hi ? b3v : rx1;
        __builtin_amdgcn_s_setprio(1);
#pragma unroll
        for (int nf = 0; nf < 4; ++nf) {
          const int dr = nf * 32 + q32;
          const int vb = (dr * 256 + sub * 128 + ks * 32 + hi * 16) ^ ((dr & 7) << 4);
          const short8v vf = *(const short8v*)((const char*)VT + vb);
          O[nf] = __builtin_amdgcn_mfma_f32_32x32x16_bf16(pu.s8, vf, O[nf], 0, 0, 0);
        }
        __builtin_amdgcn_s_setprio(0);
      }
    }
    __syncthreads();
  }

  // ---- epilogue: O rows are queries crow(r,hi); denom lives at lane q ----
  const float si = 1.0f / (Sden * 32.0f);
#pragma unroll
  for (int r = 0; r < 16; ++r) {
    const int cr = (r & 3) + 8 * (r >> 2) + 4 * hi;
    const float sio = __shfl(si, cr, 64);
    const int tok = qrow0 + cr;
#pragma unroll
    for (int nf = 0; nf < 4; ++nf)
      o[(size_t)(bb * SEQ + tok) * EMB + hh * DHEAD + nf * 32 + q32] = f2b_hw(O[nf][r] * sio);
  }
}

// ---------------- layernorm over 1024 ----------------
// MODE 0: write f32 + bf16; MODE 1: f32 only (may be in-place)
template <int MODE>
__global__ __launch_bounds__(256) void k_ln(const float* __restrict__ in,
    const float* __restrict__ gw, const float* __restrict__ bw,
    float* __restrict__ outf, u16* __restrict__ outb) {
  __shared__ float ps[4], pq[4];
  const int row = blockIdx.x;
  const int t = threadIdx.x;
  const float4 v = ((const float4*)(in + (size_t)row * EMB))[t];
  float s = v.x + v.y + v.z + v.w;
  float sq = v.x * v.x + v.y * v.y + v.z * v.z + v.w * v.w;
#pragma unroll
  for (int d = 1; d < 64; d <<= 1) { s += __shfl_xor(s, d); sq += __shfl_xor(sq, d); }
  const int l = t & 63, w = t >> 6;
  if (l == 0) { ps[w] = s; pq[w] = sq; }
  __syncthreads();
  s = ps[0] + ps[1] + ps[2] + ps[3];
  sq = pq[0] + pq[1] + pq[2] + pq[3];
  const float mean = s * (1.0f / 1024.0f);
  const float var = sq * (1.0f / 1024.0f) - mean * mean;
  const float rs = rsqrtf(var + 1e-5f);
  const float4 gv = ((const float4*)gw)[t];
  const float4 bv = ((const float4*)bw)[t];
  float4 ov;
  ov.x = (v.x - mean) * rs * gv.x + bv.x;
  ov.y = (v.y - mean) * rs * gv.y + bv.y;
  ov.z = (v.z - mean) * rs * gv.z + bv.z;
  ov.w = (v.w - mean) * rs * gv.w + bv.w;
  ((float4*)(outf + (size_t)row * EMB))[t] = ov;
  if constexpr (MODE == 0) {
    unsigned long long pk = (unsigned long long)f2b(ov.x)
        | ((unsigned long long)f2b(ov.y) << 16)
        | ((unsigned long long)f2b(ov.z) << 32)
        | ((unsigned long long)f2b(ov.w) << 48);
    ((unsigned long long*)(outb + (size_t)row * EMB))[t] = pk;
  }
}

extern "C" void kernel_launch(void* const* d_in, const int* in_sizes, int n_in,
                              void* d_out, int out_size, void* d_ws, size_t ws_size,
                              hipStream_t stream) {
  const float* x      = (const float*)d_in[0];
  const float* wqkv_w = (const float*)d_in[1];
  const float* wqkv_b = (const float*)d_in[2];
  const float* proj_w = (const float*)d_in[3];
  const float* proj_b = (const float*)d_in[4];
  const float* lin1_w = (const float*)d_in[5];
  const float* lin1_b = (const float*)d_in[6];
  const float* lin2_w = (const float*)d_in[7];
  const float* lin2_b = (const float*)d_in[8];
  const float* ln_g   = (const float*)d_in[9];
  const float* ln_b   = (const float*)d_in[10];

  char* ws = (char*)d_ws;
  // arena (bytes)
  u16*   wqkv_t = (u16*)(ws + 0);                       //  6,291,456
  u16*   proj_t = (u16*)(ws + 6291456);                 //  2,097,152
  u16*   lin1_t = (u16*)(ws + 8388608);                 //  8,388,608
  u16*   lin2_t = (u16*)(ws + 16777216);                //  8,388,608
  u16*   qbuf   = (u16*)(ws + 25165824);                // 16 MiB x3 (q,k,v)
  u16*   kbuf   = (u16*)(ws + 25165824 + 16777216);
  u16*   vbuf   = (u16*)(ws + 25165824 + 33554432);
  u16*   xb     = (u16*)(ws + 75497472);                // 16 MiB; later attn_out
  u16*   attn_o = (u16*)(ws + 75497472);
  float* res1   = (float*)(ws + 92274688);              // 32 MiB
  u16*   hbuf   = (u16*)(ws + 92274688);                // 64 MiB (over res1, later)
  float* x1f    = (float*)(ws + 25165824);              // 32 MiB (over q,k)
  u16*   x1b    = (u16*)(ws + 58720256);                // 16 MiB (over v)
  float* outf   = (float*)d_out;

  // merged prep: x->bf16 + all weight transpose-converts (one launch)
  k_prep<<<20480, 256, 0, stream>>>(x, wqkv_w, proj_w, lin1_w, lin2_w,
                                    xb, wqkv_t, proj_t, lin1_t, lin2_t);

  // QKV GEMM + head-interleave scatter (1-D swizzled grid)
  k_gemm<0><<<(3 * EMB / 128) * (M_TOK / 128), 256, 0, stream>>>(
      xb, wqkv_t, wqkv_b, nullptr, (void*)qbuf, M_TOK, 3 * EMB, EMB);
  // attention (QBLK=256, 8 waves -> 256 blocks; KVBLK=128, T15 pipeline)
  k_attn<<<dim3(SEQ / 256, HEADS, B_DIM), 512, 0, stream>>>(qbuf, kbuf, vbuf, attn_o);
  // proj + residual(x) -> res1 (f32)
  k_gemm<1><<<(EMB / 128) * (M_TOK / 128), 256, 0, stream>>>(
      attn_o, proj_t, proj_b, x, (void*)res1, M_TOK, EMB, EMB);
  // LN1 -> x1f (f32) + x1b (bf16)
  k_ln<0><<<M_TOK, 256, 0, stream>>>(res1, ln_g, ln_b, x1f, x1b);
  // lin1 + gelu -> h (bf16)
  k_gemm<2><<<(FFDIM / 128) * (M_TOK / 128), 256, 0, stream>>>(
      x1b, lin1_t, lin1_b, nullptr, (void*)hbuf, M_TOK, FFDIM, EMB);
  // lin2 + residual(x1f) -> d_out (f32, pre-LN)
  k_gemm<3><<<(EMB / 128) * (M_TOK / 128), 256, 0, stream>>>(
      hbuf, lin2_t, lin2_b, x1f, (void*)outf, M_TOK, EMB, FFDIM);
  // LN2 in-place on d_out
  k_ln<1><<<M_TOK, 256, 0, stream>>>(outf, ln_g, ln_b, outf, nullptr);
}

// Round 6
// 452.591 us; speedup vs baseline: 1.2452x; 1.0151x over previous
//
#include <hip/hip_runtime.h>
#include <hip/hip_bf16.h>
#include <math.h>

#define B_DIM 4
#define SEQ   2048
#define EMB   1024
#define HEADS 8
#define DHEAD 128
#define M_TOK (B_DIM * SEQ)   /* 8192 */
#define FFDIM (4 * EMB)       /* 4096 */

typedef unsigned short u16;
typedef __attribute__((ext_vector_type(8))) short short8v;
typedef __attribute__((ext_vector_type(4))) float float4v;
typedef __attribute__((ext_vector_type(16))) float float16v;

__device__ __forceinline__ u16 f2b(float f) {
  union { float f; unsigned u; } a; a.f = f;
  unsigned u = a.u;
  u += 0x7fffu + ((u >> 16) & 1u);   // round-to-nearest-even
  return (u16)(u >> 16);
}

// native cast: compiler pairs these into v_cvt_pk_bf16_f32
__device__ __forceinline__ u16 f2b_hw(float f) {
  __hip_bfloat16 h = __float2bfloat16(f);
  return *(u16*)&h;
}

__device__ __forceinline__ void gload16(const void* g, void* l) {
  __builtin_amdgcn_global_load_lds(
      (const __attribute__((address_space(1))) unsigned int*)g,
      (__attribute__((address_space(3))) unsigned int*)l, 16, 0, 0);
}

// all-inline gelu (tanh form; max |err| vs exact-erf gelu ~1e-3, NaN-safe)
__device__ __forceinline__ float gelu_inl(float v) {
  const float y = 0.7978845608028654f * (v + 0.044715f * v * v * v);
  const float e = __expf(2.0f * y);
  const float th = 1.0f - 2.0f / (e + 1.0f);
  return 0.5f * v * (1.0f + th);
}

// ---------------- merged prep: x->bf16 + 4 weight transpose-converts ----------
__device__ __forceinline__ void tcvt_body(const float* __restrict__ W,
    u16* __restrict__ Wt, int K, int N, int bx, int by, int tx, int ty,
    float (*t)[33]) {
  const int n0 = bx * 32, k0 = by * 32;
  for (int j = ty; j < 32; j += 8)
    t[j][tx] = W[(size_t)(k0 + j) * N + n0 + tx];
  __syncthreads();
  for (int j = ty; j < 32; j += 8)
    Wt[(size_t)(n0 + j) * K + k0 + tx] = f2b(t[tx][j]);
}

__global__ __launch_bounds__(256) void k_prep(
    const float* __restrict__ x, const float* __restrict__ wqkv_w,
    const float* __restrict__ proj_w, const float* __restrict__ lin1_w,
    const float* __restrict__ lin2_w, u16* __restrict__ xb,
    u16* __restrict__ wqkv_t, u16* __restrict__ proj_t,
    u16* __restrict__ lin1_t, u16* __restrict__ lin2_t) {
  __shared__ float t[32][33];
  const int bid = blockIdx.x, tid = threadIdx.x;
  if (bid < 8192) {  // x convert: 8192 blocks x 256 thr x float4
    const int i = bid * 256 + tid;
    const float4 v = ((const float4*)x)[i];
    unsigned long long pk = (unsigned long long)f2b(v.x)
        | ((unsigned long long)f2b(v.y) << 16)
        | ((unsigned long long)f2b(v.z) << 32)
        | ((unsigned long long)f2b(v.w) << 48);
    ((unsigned long long*)xb)[i] = pk;
    return;
  }
  const int tx = tid & 31, ty = tid >> 5;
  if (bid < 11264)
    tcvt_body(wqkv_w, wqkv_t, 1024, 3072, (bid - 8192) % 96, (bid - 8192) / 96, tx, ty, t);
  else if (bid < 12288)
    tcvt_body(proj_w, proj_t, 1024, 1024, (bid - 11264) % 32, (bid - 11264) / 32, tx, ty, t);
  else if (bid < 16384)
    tcvt_body(lin1_w, lin1_t, 1024, 4096, (bid - 12288) % 128, (bid - 12288) / 128, tx, ty, t);
  else
    tcvt_body(lin2_w, lin2_t, 4096, 1024, (bid - 16384) % 32, (bid - 16384) / 32, tx, ty, t);
}

// ---------------- GEMM: C[M,N] = A[M,K](bf16) @ Bt[N,K]^T(bf16) + epilogue ----
// 1-D grid with bijective XCD swizzle (T1). Proven 128^2 2-phase structure.
// EPI 0: QKV bias + head-interleave scatter (bf16)
// EPI 1: bias + residual(res f32) -> f32
// EPI 2: bias + gelu -> bf16
// EPI 3: bias + fused-LN1-residual: out = v + (res1-mean)*rs*g+b (f32)
template <int EPI>
__global__ __launch_bounds__(256, 2) void k_gemm(
    const u16* __restrict__ A, const u16* __restrict__ Bt,
    const float* __restrict__ bias, const float* __restrict__ res,
    void* __restrict__ out0, int M, int N, int K,
    const float2* __restrict__ lnst, const float* __restrict__ lng,
    const float* __restrict__ lnb) {
  __shared__ __align__(16) u16 lds[2][2][128][32];
  const int tid = threadIdx.x;
  const int l = tid & 63, w = tid >> 6;
  const int g = l >> 4, lm = l & 15;
  const int wm = w >> 1, wn = w & 1;

  const int NBX = N >> 7;
  const int nwg = NBX * (M >> 7);
  const int wg = blockIdx.x;
  const int swz = (wg & 7) * (nwg >> 3) + (wg >> 3);   // nwg % 8 == 0 always here
  const int tn = swz % NBX, tm = swz / NBX;

  const size_t arow0 = (size_t)tm * 128;
  const size_t brow0 = (size_t)tn * 128;
  const int srow = l >> 2;          // 0..15 within a 16-row chunk
  const int scol = (l & 3) * 8;     // element offset within row

  float4v acc[4][4];
  const float4v vzero = {0.f, 0.f, 0.f, 0.f};
#pragma unroll
  for (int i = 0; i < 4; ++i)
#pragma unroll
    for (int j = 0; j < 4; ++j) acc[i][j] = vzero;

  const int nt = K / 32;
  auto stage = [&](int t, int buf) {
    const int k0 = t * 32;
#pragma unroll
    for (int i = 0; i < 2; ++i) {
      const int r = w * 32 + i * 16 + srow;
      gload16(A + (arow0 + r) * (size_t)K + k0 + scol, &lds[buf][0][w * 32 + i * 16][0]);
      gload16(Bt + (brow0 + r) * (size_t)K + k0 + scol, &lds[buf][1][w * 32 + i * 16][0]);
    }
  };

  stage(0, 0);
  __syncthreads();
  for (int t = 0; t < nt; ++t) {
    const int buf = t & 1;
    if (t + 1 < nt) stage(t + 1, buf ^ 1);
    short8v af[4], bf[4];
#pragma unroll
    for (int mf = 0; mf < 4; ++mf)
      af[mf] = *(const short8v*)&lds[buf][0][wm * 64 + mf * 16 + lm][g * 8];
#pragma unroll
    for (int nf = 0; nf < 4; ++nf)
      bf[nf] = *(const short8v*)&lds[buf][1][wn * 64 + nf * 16 + lm][g * 8];
#pragma unroll
    for (int mf = 0; mf < 4; ++mf)
#pragma unroll
      for (int nf = 0; nf < 4; ++nf)
        acc[mf][nf] = __builtin_amdgcn_mfma_f32_16x16x32_bf16(af[mf], bf[nf], acc[mf][nf], 0, 0, 0);
    __syncthreads();
  }

#pragma unroll
  for (int mf = 0; mf < 4; ++mf)
#pragma unroll
    for (int nf = 0; nf < 4; ++nf)
#pragma unroll
      for (int r = 0; r < 4; ++r) {
        const int row = tm * 128 + wm * 64 + mf * 16 + 4 * g + r;
        const int col = tn * 128 + wn * 64 + nf * 16 + lm;
        float v = acc[mf][nf][r] + bias[col];
        if constexpr (EPI == 0) {
          const int hh = col / 384;
          const int rem = col - hh * 384;
          const int d = rem / 3;
          const int wv = rem - d * 3;
          const int btok = row >> 11, ntok = row & 2047;
          u16* dst = (u16*)out0 + (size_t)wv * ((size_t)M_TOK * EMB)
                   + (((size_t)(btok * HEADS + hh) * SEQ + ntok) * DHEAD + d);
          *dst = f2b(v);
        } else if constexpr (EPI == 2) {
          ((u16*)out0)[(size_t)row * N + col] = f2b(gelu_inl(v));
        } else if constexpr (EPI == 3) {
          // fused LN1 residual: identical f32 expression k_ln used to emit x1f
          const size_t idx = (size_t)row * N + col;
          const float2 st = lnst[row];
          const float xv = (res[idx] - st.x) * st.y * lng[col] + lnb[col];
          ((float*)out0)[idx] = v + xv;
        } else {
          const size_t idx = (size_t)row * N + col;
          ((float*)out0)[idx] = v + res[idx];
        }
      }
}

// ---------------- flash attention: swapped-QK^T 32x32, QBLK=256, KVBLK=128 ----
// q,k,v: bf16 [b,h,2048,128]; o: bf16 [8192,1024] (token-major, h*128+d cols)
// EXACT round-0 structure (best measured: 112.4 us). 8 waves x 32 q-rows;
// 128-key tiles as 2 sub-tiles of 64, one barrier pair per 128 keys.
// XOR-swizzled K/VT (64 KiB), in-register softmax/P, defer-max, cvt_pk
// P-pack, setprio on MFMA. Structural floor: only 2048 wave-units exist ->
// 8 waves/CU max; split-KV (r4), dbuf (r1), 2-block (r2), T15 (r5) all null
// or negative -- the per-wave serial softmax chain is the floor.
__global__ __launch_bounds__(512, 2) void k_attn(
    const u16* __restrict__ q, const u16* __restrict__ k,
    const u16* __restrict__ v, u16* __restrict__ o) {
  __shared__ __align__(16) u16 KT[128 * 128];  // [key][d] swizzled, rows 256 B
  __shared__ __align__(16) u16 VT[128 * 128];  // [d][key] swizzled, rows 256 B
  const int tid = threadIdx.x;
  const int l = tid & 63, w = tid >> 6;        // w 0..7
  const int q32 = l & 31, hi = l >> 5;
  const int qt = blockIdx.x, hh = blockIdx.y, bb = blockIdx.z;
  const size_t base = (size_t)(bb * HEADS + hh) * SEQ * DHEAD;
  const int qrow0 = qt * 256 + w * 32;

  // Q fragments (B-operand): lane holds Q[q32][c*16 + hi*8 .. +7]
  short8v qf[8];
#pragma unroll
  for (int c = 0; c < 8; ++c)
    qf[c] = *(const short8v*)(q + base + (size_t)(qrow0 + q32) * DHEAD + c * 16 + hi * 8);

  float m = -1e30f, Sden = 0.f;
  float16v O[4];
#pragma unroll
  for (int nf = 0; nf < 4; ++nf)
#pragma unroll
    for (int r = 0; r < 16; ++r) O[nf][r] = 0.f;

  const int krow = tid >> 4;            // 0..31 (row within 32-row sweep)
  const int kseg = (tid & 15) * 16;     // byte col within 256-B row
  const int vp = tid & 31, vdg = tid >> 5;   // vdg 0..15

  for (int kvt = 0; kvt < 16; ++kvt) {
    const size_t kvbase = base + (size_t)kvt * 128 * DHEAD;
    // ---- stage K (128 keys) via global_load_lds: linear dest, pre-swz src ----
#pragma unroll
    for (int s = 0; s < 4; ++s) {
      const int r = s * 32 + krow;
      const int csrc = kseg ^ ((r & 7) << 4);
      gload16(k + kvbase + r * DHEAD + (csrc >> 1), (u16*)KT + s * 4096 + tid * 8);
    }
    // ---- stage V transposed (128 keys) with swizzled writes: VT[d][key] ----
#pragma unroll
    for (int kk = 0; kk < 2; ++kk) {
      const int d0 = vdg * 8;
      const u16* s0p = v + kvbase + (size_t)(kk * 64 + 2 * vp) * DHEAD + d0;
      const short8v a = *(const short8v*)s0p;
      const short8v b2 = *(const short8v*)(s0p + DHEAD);
#pragma unroll
      for (int j = 0; j < 8; ++j) {
        const unsigned pk = ((unsigned)(u16)a[j]) | (((unsigned)(u16)b2[j]) << 16);
        const int byte = ((d0 + j) * 256 + kk * 128 + 4 * vp) ^ (((d0 + j) & 7) << 4);
        *(unsigned*)((char*)VT + byte) = pk;
      }
    }
    __syncthreads();

#pragma unroll
    for (int sub = 0; sub < 2; ++sub) {
      // ---- QK^T swapped: S[key][q] = mfma(A=K, B=Q); lane q = q32 ----
      float16v S0, S1;
#pragma unroll
      for (int r = 0; r < 16; ++r) { S0[r] = 0.f; S1[r] = 0.f; }
      __builtin_amdgcn_s_setprio(1);
#pragma unroll
      for (int c = 0; c < 8; ++c) {
        const int cb = (c * 32 + hi * 16) ^ ((q32 & 7) << 4);
        const short8v kf0 = *(const short8v*)((const char*)KT + (sub * 64 + q32) * 256 + cb);
        const short8v kf1 = *(const short8v*)((const char*)KT + (sub * 64 + 32 + q32) * 256 + cb);
        S0 = __builtin_amdgcn_mfma_f32_32x32x16_bf16(kf0, qf[c], S0, 0, 0, 0);
        S1 = __builtin_amdgcn_mfma_f32_32x32x16_bf16(kf1, qf[c], S1, 0, 0, 0);
      }
      __builtin_amdgcn_s_setprio(0);

      // ---- in-register softmax for query q32 (keys split across hi) ----
      float pm = -1e30f;
#pragma unroll
      for (int r = 0; r < 16; ++r) pm = fmaxf(pm, fmaxf(S0[r], S1[r]));
      pm = fmaxf(pm, __shfl_xor(pm, 32));
      if (!__all(pm <= m + 8.0f)) {      // defer-max
        const float nm = fmaxf(m, pm);
        const float rsc = __expf(m - nm);
        m = nm;
        Sden *= rsc;
#pragma unroll
        for (int r = 0; r < 16; ++r) {
          const float rr_ = __shfl(rsc, (r & 3) + 8 * (r >> 2) + 4 * hi, 64);
#pragma unroll
          for (int nf = 0; nf < 4; ++nf) O[nf][r] *= rr_;
        }
      }
      float ps = 0.f;
#pragma unroll
      for (int r = 0; r < 16; ++r) { S0[r] = __expf(S0[r] - m); ps += S0[r]; }
#pragma unroll
      for (int r = 0; r < 16; ++r) { S1[r] = __expf(S1[r] - m); ps += S1[r]; }
      ps += __shfl_xor(ps, 32);
      Sden += ps;

      // ---- pack P to bf16 pairs (native casts -> cvt_pk) ----
      unsigned u0[8], u1[8];
#pragma unroll
      for (int j = 0; j < 8; ++j) {
        u0[j] = (unsigned)f2b_hw(S0[2 * j]) | ((unsigned)f2b_hw(S0[2 * j + 1]) << 16);
        u1[j] = (unsigned)f2b_hw(S1[2 * j]) | ((unsigned)f2b_hw(S1[2 * j + 1]) << 16);
      }

      // ---- PV: build A-frags via one cross-half swap per pair, 16 MFMA ----
#pragma unroll
      for (int ks = 0; ks < 4; ++ks) {
        const int k1 = ks & 1;
        unsigned b0v, b1v, b2v, b3v;
        if (ks < 2) { b0v = u0[4 * k1]; b1v = u0[4 * k1 + 1]; b2v = u0[4 * k1 + 2]; b3v = u0[4 * k1 + 3]; }
        else        { b0v = u1[4 * k1]; b1v = u1[4 * k1 + 1]; b2v = u1[4 * k1 + 2]; b3v = u1[4 * k1 + 3]; }
        const unsigned send0 = hi ? b0v : b2v;
        const unsigned send1 = hi ? b1v : b3v;
        const unsigned rx0 = (unsigned)__shfl_xor((int)send0, 32);
        const unsigned rx1 = (unsigned)__shfl_xor((int)send1, 32);
        union { unsigned uu[4]; short8v s8; } pu;
        pu.uu[0] = hi ? rx0 : b0v;
        pu.uu[1] = hi ? rx1 : b1v;
        pu.uu[2] = hi ? b2v : rx0;
        pu.uu[3] = hi ? b3v : rx1;
        __builtin_amdgcn_s_setprio(1);
#pragma unroll
        for (int nf = 0; nf < 4; ++nf) {
          const int dr = nf * 32 + q32;
          const int vb = (dr * 256 + sub * 128 + ks * 32 + hi * 16) ^ ((dr & 7) << 4);
          const short8v vf = *(const short8v*)((const char*)VT + vb);
          O[nf] = __builtin_amdgcn_mfma_f32_32x32x16_bf16(pu.s8, vf, O[nf], 0, 0, 0);
        }
        __builtin_amdgcn_s_setprio(0);
      }
    }
    __syncthreads();
  }

  // ---- epilogue: O rows are queries crow(r,hi); denom lives at lane q ----
  const float si = 1.0f / (Sden * 32.0f);
#pragma unroll
  for (int r = 0; r < 16; ++r) {
    const int cr = (r & 3) + 8 * (r >> 2) + 4 * hi;
    const float sio = __shfl(si, cr, 64);
    const int tok = qrow0 + cr;
#pragma unroll
    for (int nf = 0; nf < 4; ++nf)
      o[(size_t)(bb * SEQ + tok) * EMB + hh * DHEAD + nf * 32 + q32] = f2b_hw(O[nf][r] * sio);
  }
}

// ---------------- layernorm over 1024 ----------------
// MODE 0: write bf16 + per-row (mean, rstd) stats (f32 residual recomputed
//         in the lin2 epilogue from the same f32 inputs -> saves 32 MB write)
// MODE 1: f32 only (may be in-place)
template <int MODE>
__global__ __launch_bounds__(256) void k_ln(const float* __restrict__ in,
    const float* __restrict__ gw, const float* __restrict__ bw,
    float* __restrict__ outf, u16* __restrict__ outb,
    float2* __restrict__ stats) {
  __shared__ float ps[4], pq[4];
  const int row = blockIdx.x;
  const int t = threadIdx.x;
  const float4 v = ((const float4*)(in + (size_t)row * EMB))[t];
  float s = v.x + v.y + v.z + v.w;
  float sq = v.x * v.x + v.y * v.y + v.z * v.z + v.w * v.w;
#pragma unroll
  for (int d = 1; d < 64; d <<= 1) { s += __shfl_xor(s, d); sq += __shfl_xor(sq, d); }
  const int l = t & 63, w = t >> 6;
  if (l == 0) { ps[w] = s; pq[w] = sq; }
  __syncthreads();
  s = ps[0] + ps[1] + ps[2] + ps[3];
  sq = pq[0] + pq[1] + pq[2] + pq[3];
  const float mean = s * (1.0f / 1024.0f);
  const float var = sq * (1.0f / 1024.0f) - mean * mean;
  const float rs = rsqrtf(var + 1e-5f);
  const float4 gv = ((const float4*)gw)[t];
  const float4 bv = ((const float4*)bw)[t];
  float4 ov;
  ov.x = (v.x - mean) * rs * gv.x + bv.x;
  ov.y = (v.y - mean) * rs * gv.y + bv.y;
  ov.z = (v.z - mean) * rs * gv.z + bv.z;
  ov.w = (v.w - mean) * rs * gv.w + bv.w;
  if constexpr (MODE == 0) {
    unsigned long long pk = (unsigned long long)f2b(ov.x)
        | ((unsigned long long)f2b(ov.y) << 16)
        | ((unsigned long long)f2b(ov.z) << 32)
        | ((unsigned long long)f2b(ov.w) << 48);
    ((unsigned long long*)(outb + (size_t)row * EMB))[t] = pk;
    if (t == 0) stats[row] = make_float2(mean, rs);
  } else {
    ((float4*)(outf + (size_t)row * EMB))[t] = ov;
  }
}

extern "C" void kernel_launch(void* const* d_in, const int* in_sizes, int n_in,
                              void* d_out, int out_size, void* d_ws, size_t ws_size,
                              hipStream_t stream) {
  const float* x      = (const float*)d_in[0];
  const float* wqkv_w = (const float*)d_in[1];
  const float* wqkv_b = (const float*)d_in[2];
  const float* proj_w = (const float*)d_in[3];
  const float* proj_b = (const float*)d_in[4];
  const float* lin1_w = (const float*)d_in[5];
  const float* lin1_b = (const float*)d_in[6];
  const float* lin2_w = (const float*)d_in[7];
  const float* lin2_b = (const float*)d_in[8];
  const float* ln_g   = (const float*)d_in[9];
  const float* ln_b   = (const float*)d_in[10];

  char* ws = (char*)d_ws;
  // arena (bytes); live-range verified:
  //  stats  [0, 64K)            written LN1 (wqkv_t dead by then), read lin2
  //  wqkv_t [0, 6.3M)           prep -> QKV gemm
  //  proj_t [6.3M, 8.4M)        prep -> proj gemm
  //  lin1_t [8.4M, 16.8M)       prep -> lin1 gemm
  //  lin2_t [16.8M, 25.2M)      prep -> lin2 gemm
  //  q/k/v  [25.2M, 75.5M)      QKV gemm -> attn
  //  xb     [75.5M, 92.3M)      prep -> QKV gemm; then attn_o (attn -> proj)
  //  res1   [88MiB, 120MiB)     proj -> LN1 AND lin2 (fused-LN residual)
  //  hbuf   [24MiB, 88MiB)      lin1 -> lin2 (over dead q/k/v/xb head)
  //  x1b    [120MiB, 136MiB)    LN1 -> lin1 (ws >= 152MiB proven in r4)
  u16*   wqkv_t = (u16*)(ws + 0);
  u16*   proj_t = (u16*)(ws + 6291456);
  u16*   lin1_t = (u16*)(ws + 8388608);
  u16*   lin2_t = (u16*)(ws + 16777216);
  u16*   qbuf   = (u16*)(ws + 25165824);
  u16*   kbuf   = (u16*)(ws + 25165824 + 16777216);
  u16*   vbuf   = (u16*)(ws + 25165824 + 33554432);
  u16*   xb     = (u16*)(ws + 75497472);
  u16*   attn_o = (u16*)(ws + 75497472);
  float* res1   = (float*)(ws + 92274688);
  u16*   hbuf   = (u16*)(ws + 25165824);               // 64 MiB, ends 92274688
  u16*   x1b    = (u16*)(ws + 125829120);              // 16 MiB
  float2* lnst  = (float2*)(ws + 0);                   // 64 KiB row stats
  float* outf   = (float*)d_out;

  // merged prep: x->bf16 + all weight transpose-converts (one launch)
  k_prep<<<20480, 256, 0, stream>>>(x, wqkv_w, proj_w, lin1_w, lin2_w,
                                    xb, wqkv_t, proj_t, lin1_t, lin2_t);

  // QKV GEMM + head-interleave scatter (1-D swizzled grid)
  k_gemm<0><<<(3 * EMB / 128) * (M_TOK / 128), 256, 0, stream>>>(
      xb, wqkv_t, wqkv_b, nullptr, (void*)qbuf, M_TOK, 3 * EMB, EMB,
      nullptr, nullptr, nullptr);
  // attention (QBLK=256, 8 waves -> 256 blocks; KVBLK=128)
  k_attn<<<dim3(SEQ / 256, HEADS, B_DIM), 512, 0, stream>>>(qbuf, kbuf, vbuf, attn_o);
  // proj + residual(x) -> res1 (f32)
  k_gemm<1><<<(EMB / 128) * (M_TOK / 128), 256, 0, stream>>>(
      attn_o, proj_t, proj_b, x, (void*)res1, M_TOK, EMB, EMB,
      nullptr, nullptr, nullptr);
  // LN1 -> x1b (bf16) + per-row stats (no f32 write)
  k_ln<0><<<M_TOK, 256, 0, stream>>>(res1, ln_g, ln_b, nullptr, x1b, lnst);
  // lin1 + gelu -> h (bf16)
  k_gemm<2><<<(FFDIM / 128) * (M_TOK / 128), 256, 0, stream>>>(
      x1b, lin1_t, lin1_b, nullptr, (void*)hbuf, M_TOK, FFDIM, EMB,
      nullptr, nullptr, nullptr);
  // lin2 + fused LN1-residual (recomputed from res1 + stats) -> d_out (f32)
  k_gemm<3><<<(EMB / 128) * (M_TOK / 128), 256, 0, stream>>>(
      hbuf, lin2_t, lin2_b, res1, (void*)outf, M_TOK, EMB, FFDIM,
      lnst, ln_g, ln_b);
  // LN2 in-place on d_out
  k_ln<1><<<M_TOK, 256, 0, stream>>>(outf, ln_g, ln_b, outf, nullptr, nullptr);
}